// Round 5
// baseline (2028.872 us; speedup 1.0000x reference)
//
#include <hip/hip_runtime.h>

#define DH  30
#define DHP 32
#define SLOPE 0.01f
// full scheduler fence: keeps the live set row-local in the unrolled body
#define SB() __builtin_amdgcn_sched_barrier(0)

// 4 waves/EU min => VGPR cap 128: true live set ~100, so no spills, 4x occupancy
__global__ __launch_bounds__(256, 4) void mlp_fwdbwd(
    const float4* __restrict__ pe,
    const float*  __restrict__ q,
    const float4* __restrict__ s,
    const float*  __restrict__ gW1, const float* __restrict__ gb1,
    const float*  __restrict__ gW2, const float* __restrict__ gb2,
    const float*  __restrict__ gW3, const float* __restrict__ gb3,
    const float*  __restrict__ gW4, const float* __restrict__ gb4,
    float* __restrict__ dout, int n)
{
    __shared__ float sW1[9][DHP];
    __shared__ float sW2[DH][DHP];
    __shared__ float sW3[DH][DHP];
    __shared__ float sB1[DHP], sB2[DHP], sB3[DHP], sW4[DHP];
    __shared__ float sB4;

    const int tid = threadIdx.x;
    for (int idx = tid; idx < 9 * DHP; idx += 256) {
        int r = idx >> 5, c = idx & 31;
        sW1[r][c] = (c < DH) ? gW1[r * DH + c] : 0.f;
    }
    for (int idx = tid; idx < DH * DHP; idx += 256) {
        int r = idx >> 5, c = idx & 31;
        sW2[r][c] = (c < DH) ? gW2[r * DH + c] : 0.f;
        sW3[r][c] = (c < DH) ? gW3[r * DH + c] : 0.f;
    }
    if (tid < DHP) {
        sB1[tid] = (tid < DH) ? gb1[tid] : 0.f;
        sB2[tid] = (tid < DH) ? gb2[tid] : 0.f;
        sB3[tid] = (tid < DH) ? gb3[tid] : 0.f;
        sW4[tid] = (tid < DH) ? gW4[tid] : 0.f;
    }
    if (tid == 0) sB4 = gb4[0];
    __syncthreads();

    const int i = blockIdx.x * 256 + tid;
    if (i >= n) return;

    const float4 vpe = pe[i];
    const float4 vs  = s[i];
    const float  vq  = q[i];
    float x[9] = { vpe.x, vpe.y, vpe.z, vpe.w, vq, vs.x, vs.y, vs.z, vs.w };

    float acc[DH];
    float h[DH];
    unsigned m1 = 0, m2 = 0, m3 = 0;

    // ---- layer 1: (x @ W1) then + b1  (BLAS semantics: acc from 0, k ascending, FMA) ----
    #pragma unroll
    for (int j = 0; j < DH; ++j) acc[j] = 0.f;
    #pragma unroll
    for (int k = 0; k < 9; ++k) {
        const float xk = x[k];
        #pragma unroll
        for (int j = 0; j < DH; ++j) acc[j] = fmaf(xk, sW1[k][j], acc[j]);
        SB();
    }
    #pragma unroll
    for (int j = 0; j < DH; ++j) {
        const float z = acc[j] + sB1[j];
        if (z > 0.f) m1 |= (1u << j);
        h[j] = (z > 0.f) ? z : SLOPE * z;
    }
    SB();

    // ---- layer 2 ----
    #pragma unroll
    for (int j = 0; j < DH; ++j) acc[j] = 0.f;
    #pragma unroll
    for (int k = 0; k < DH; ++k) {
        const float hk = h[k];
        #pragma unroll
        for (int j = 0; j < DH; ++j) acc[j] = fmaf(hk, sW2[k][j], acc[j]);
        SB();
    }
    #pragma unroll
    for (int j = 0; j < DH; ++j) {
        const float z = acc[j] + sB2[j];
        if (z > 0.f) m2 |= (1u << j);
        h[j] = (z > 0.f) ? z : SLOPE * z;
    }
    SB();

    // ---- layer 3 ----
    #pragma unroll
    for (int j = 0; j < DH; ++j) acc[j] = 0.f;
    #pragma unroll
    for (int k = 0; k < DH; ++k) {
        const float hk = h[k];
        #pragma unroll
        for (int j = 0; j < DH; ++j) acc[j] = fmaf(hk, sW3[k][j], acc[j]);
        SB();
    }
    float outv = 0.f;
    #pragma unroll
    for (int j = 0; j < DH; ++j) {
        const float z = acc[j] + sB3[j];
        if (z > 0.f) m3 |= (1u << j);
        const float hz = (z > 0.f) ? z : SLOPE * z;
        outv = fmaf(hz, sW4[j], outv);
    }
    outv += sB4;
    SB();

    // ---- backward (f32, mask-driven; 4-way split dots — backward is value-continuous) ----
    float g[DHP];
    #pragma unroll
    for (int j = 0; j < DHP; ++j) {
        const float w = sW4[j];
        g[j] = ((m3 >> j) & 1u) ? w : SLOPE * w;   // pads: sW4=0 -> g=0
    }
    float g2[DHP];
    #pragma unroll
    for (int k = 0; k < DH; ++k) {
        float d0 = 0.f, d1 = 0.f, d2 = 0.f, d3 = 0.f;
        #pragma unroll
        for (int j = 0; j < DHP; j += 4) {
            d0 = fmaf(g[j+0], sW3[k][j+0], d0);
            d1 = fmaf(g[j+1], sW3[k][j+1], d1);
            d2 = fmaf(g[j+2], sW3[k][j+2], d2);
            d3 = fmaf(g[j+3], sW3[k][j+3], d3);
        }
        const float dot = (d0 + d1) + (d2 + d3);
        g2[k] = ((m2 >> k) & 1u) ? dot : SLOPE * dot;
        SB();
    }
    g2[30] = 0.f; g2[31] = 0.f;
    #pragma unroll
    for (int k = 0; k < DH; ++k) {
        float d0 = 0.f, d1 = 0.f, d2 = 0.f, d3 = 0.f;
        #pragma unroll
        for (int j = 0; j < DHP; j += 4) {
            d0 = fmaf(g2[j+0], sW2[k][j+0], d0);
            d1 = fmaf(g2[j+1], sW2[k][j+1], d1);
            d2 = fmaf(g2[j+2], sW2[k][j+2], d2);
            d3 = fmaf(g2[j+3], sW2[k][j+3], d3);
        }
        const float dot = (d0 + d1) + (d2 + d3);
        g[k] = ((m1 >> k) & 1u) ? dot : SLOPE * dot;
        SB();
    }
    g[30] = 0.f; g[31] = 0.f;
    float gx[9];
    #pragma unroll
    for (int k = 0; k < 9; ++k) {
        float d0 = 0.f, d1 = 0.f, d2 = 0.f, d3 = 0.f;
        #pragma unroll
        for (int j = 0; j < DHP; j += 4) {
            d0 = fmaf(g[j+0], sW1[k][j+0], d0);
            d1 = fmaf(g[j+1], sW1[k][j+1], d1);
            d2 = fmaf(g[j+2], sW1[k][j+2], d2);
            d3 = fmaf(g[j+3], sW1[k][j+3], d3);
        }
        gx[k] = (d0 + d1) + (d2 + d3);
        SB();
    }

    // ---- stores: [out(N) | h_s(4N) | h_q(N) | h_pe(4N)] ----
    dout[i] = outv;
    float4* hs = reinterpret_cast<float4*>(dout + (size_t)n);
    hs[i] = make_float4(gx[5], gx[6], gx[7], gx[8]);
    dout[(size_t)5 * n + i] = gx[4];
    float4* hpe = reinterpret_cast<float4*>(dout + (size_t)6 * n);
    hpe[i] = make_float4(gx[0], gx[1], gx[2], gx[3]);
}

extern "C" void kernel_launch(void* const* d_in, const int* in_sizes, int n_in,
                              void* d_out, int out_size, void* d_ws, size_t ws_size,
                              hipStream_t stream) {
    const int n = in_sizes[1];  // input_q has N elements
    const int blocks = (n + 255) / 256;
    hipLaunchKernelGGL(mlp_fwdbwd, dim3(blocks), dim3(256), 0, stream,
        (const float4*)d_in[0], (const float*)d_in[1], (const float4*)d_in[2],
        (const float*)d_in[3], (const float*)d_in[4],
        (const float*)d_in[5], (const float*)d_in[6],
        (const float*)d_in[7], (const float*)d_in[8],
        (const float*)d_in[9], (const float*)d_in[10],
        (float*)d_out, n);
}

// Round 6
// 254.049 us; speedup vs baseline: 7.9861x; 7.9861x over previous
//
#include <hip/hip_runtime.h>

#define DH 30
#define SLOPE 0.01f

// Weights are wave-uniform at compile-time-constant offsets: read them
// directly from global via the scalar pipe (s_load -> SGPR -> v_fma with
// SGPR operand). No LDS, no staging, no __syncthreads.
__global__ __launch_bounds__(256) void mlp_fwdbwd(
    const float4* __restrict__ pe,
    const float*  __restrict__ q,
    const float4* __restrict__ s,
    const float* __restrict__ W1, const float* __restrict__ b1,
    const float* __restrict__ W2, const float* __restrict__ b2,
    const float* __restrict__ W3, const float* __restrict__ b3,
    const float* __restrict__ W4, const float* __restrict__ b4,
    float* __restrict__ dout, int n)
{
    const int i = blockIdx.x * 256 + threadIdx.x;
    if (i >= n) return;

    const float4 vpe = pe[i];
    const float4 vs  = s[i];
    const float  vq  = q[i];
    float x[9] = { vpe.x, vpe.y, vpe.z, vpe.w, vq, vs.x, vs.y, vs.z, vs.w };

    float acc[DH];
    float h[DH];
    unsigned m1 = 0, m2 = 0, m3 = 0;

    // ---- layer 1: (x @ W1) then + b1 (BLAS semantics: acc from 0, k ascending, FMA) ----
    #pragma unroll
    for (int j = 0; j < DH; ++j) acc[j] = 0.f;
    #pragma unroll
    for (int k = 0; k < 9; ++k) {
        const float xk = x[k];
        #pragma unroll
        for (int j = 0; j < DH; ++j) acc[j] = fmaf(xk, W1[k * DH + j], acc[j]);
    }
    #pragma unroll
    for (int j = 0; j < DH; ++j) {
        const float z = acc[j] + b1[j];
        if (z > 0.f) m1 |= (1u << j);
        h[j] = (z > 0.f) ? z : SLOPE * z;
    }

    // ---- layer 2 ----
    #pragma unroll
    for (int j = 0; j < DH; ++j) acc[j] = 0.f;
    #pragma unroll
    for (int k = 0; k < DH; ++k) {
        const float hk = h[k];
        #pragma unroll
        for (int j = 0; j < DH; ++j) acc[j] = fmaf(hk, W2[k * DH + j], acc[j]);
    }
    #pragma unroll
    for (int j = 0; j < DH; ++j) {
        const float z = acc[j] + b2[j];
        if (z > 0.f) m2 |= (1u << j);
        h[j] = (z > 0.f) ? z : SLOPE * z;
    }

    // ---- layer 3 + output dot ----
    #pragma unroll
    for (int j = 0; j < DH; ++j) acc[j] = 0.f;
    #pragma unroll
    for (int k = 0; k < DH; ++k) {
        const float hk = h[k];
        #pragma unroll
        for (int j = 0; j < DH; ++j) acc[j] = fmaf(hk, W3[k * DH + j], acc[j]);
    }
    float outv = 0.f;
    #pragma unroll
    for (int j = 0; j < DH; ++j) {
        const float z = acc[j] + b3[j];
        if (z > 0.f) m3 |= (1u << j);
        const float hz = (z > 0.f) ? z : SLOPE * z;
        outv = fmaf(hz, W4[j], outv);
    }
    outv += b4[0];

    // ---- backward (mask-driven; value-continuous, 4-way split dots) ----
    float g[DH];
    #pragma unroll
    for (int j = 0; j < DH; ++j) {
        const float w = W4[j];
        g[j] = ((m3 >> j) & 1u) ? w : SLOPE * w;
    }
    float g2[DH];
    #pragma unroll
    for (int k = 0; k < DH; ++k) {
        float d0 = 0.f, d1 = 0.f, d2 = 0.f, d3 = 0.f;
        #pragma unroll
        for (int j = 0; j < 28; j += 4) {
            d0 = fmaf(g[j+0], W3[k * DH + j+0], d0);
            d1 = fmaf(g[j+1], W3[k * DH + j+1], d1);
            d2 = fmaf(g[j+2], W3[k * DH + j+2], d2);
            d3 = fmaf(g[j+3], W3[k * DH + j+3], d3);
        }
        d0 = fmaf(g[28], W3[k * DH + 28], d0);
        d1 = fmaf(g[29], W3[k * DH + 29], d1);
        const float dot = (d0 + d1) + (d2 + d3);
        g2[k] = ((m2 >> k) & 1u) ? dot : SLOPE * dot;
    }
    #pragma unroll
    for (int k = 0; k < DH; ++k) {
        float d0 = 0.f, d1 = 0.f, d2 = 0.f, d3 = 0.f;
        #pragma unroll
        for (int j = 0; j < 28; j += 4) {
            d0 = fmaf(g2[j+0], W2[k * DH + j+0], d0);
            d1 = fmaf(g2[j+1], W2[k * DH + j+1], d1);
            d2 = fmaf(g2[j+2], W2[k * DH + j+2], d2);
            d3 = fmaf(g2[j+3], W2[k * DH + j+3], d3);
        }
        d0 = fmaf(g2[28], W2[k * DH + 28], d0);
        d1 = fmaf(g2[29], W2[k * DH + 29], d1);
        const float dot = (d0 + d1) + (d2 + d3);
        g[k] = ((m1 >> k) & 1u) ? dot : SLOPE * dot;
    }
    float gx[9];
    #pragma unroll
    for (int k = 0; k < 9; ++k) {
        float d0 = 0.f, d1 = 0.f, d2 = 0.f, d3 = 0.f;
        #pragma unroll
        for (int j = 0; j < 28; j += 4) {
            d0 = fmaf(g[j+0], W1[k * DH + j+0], d0);
            d1 = fmaf(g[j+1], W1[k * DH + j+1], d1);
            d2 = fmaf(g[j+2], W1[k * DH + j+2], d2);
            d3 = fmaf(g[j+3], W1[k * DH + j+3], d3);
        }
        d0 = fmaf(g[28], W1[k * DH + 28], d0);
        d1 = fmaf(g[29], W1[k * DH + 29], d1);
        gx[k] = (d0 + d1) + (d2 + d3);
    }

    // ---- stores: [out(N) | h_s(4N) | h_q(N) | h_pe(4N)] ----
    dout[i] = outv;
    float4* hs = reinterpret_cast<float4*>(dout + (size_t)n);
    hs[i] = make_float4(gx[5], gx[6], gx[7], gx[8]);
    dout[(size_t)5 * n + i] = gx[4];
    float4* hpe = reinterpret_cast<float4*>(dout + (size_t)6 * n);
    hpe[i] = make_float4(gx[0], gx[1], gx[2], gx[3]);
}

extern "C" void kernel_launch(void* const* d_in, const int* in_sizes, int n_in,
                              void* d_out, int out_size, void* d_ws, size_t ws_size,
                              hipStream_t stream) {
    const int n = in_sizes[1];  // input_q has N elements
    const int blocks = (n + 255) / 256;
    hipLaunchKernelGGL(mlp_fwdbwd, dim3(blocks), dim3(256), 0, stream,
        (const float4*)d_in[0], (const float*)d_in[1], (const float4*)d_in[2],
        (const float*)d_in[3], (const float*)d_in[4],
        (const float*)d_in[5], (const float*)d_in[6],
        (const float*)d_in[7], (const float*)d_in[8],
        (const float*)d_in[9], (const float*)d_in[10],
        (float*)d_out, n);
}